// Round 5
// baseline (644.499 us; speedup 1.0000x reference)
//
#include <hip/hip_runtime.h>

// Involution (RedNet-style), N=4 C=256 H=W=56, K=7, G=16, ratio=4 (Cr=64).
// k0: fold BN into w1f/bf; transpose w2 -> w2t[o][g][64] (padded, aligned).
// k1: conv1 GEMM  t[o][px] = relu(<x[:,px], w1f[:,o]> + bf[o]).
// k2: per-lane ker[49] accumulators streamed from t (outer product over o,
//     contiguous wide s_loads of w2t), then direct x gather. No LDS, no sync.

namespace {
constexpr int Nn  = 4;
constexpr int Cc  = 256;
constexpr int Hh  = 56;
constexpr int Ww  = 56;
constexpr int HW  = Hh * Ww;        // 3136
constexpr int NPX = Nn * HW;        // 12544
constexpr int KK  = 49;             // 7x7
constexpr int Cr  = 64;             // reduced channels
constexpr int Gg  = 16;             // groups

// workspace layout (floats)
constexpr int WS_W1F = 0;                   // [256][64]   16384
constexpr int WS_BF  = WS_W1F + Cc * Cr;    // [64]        64
constexpr int WS_W2T = WS_BF + Cr;          // [64][16][64] 65536 (256B-aligned rows)
constexpr int WS_T   = WS_W2T + Cr * Gg * 64; // [64][12544]
}

// ---------------------------------------------------------------------------
// k0: weight prep.  w1f[c][o] = w1[o][c]*sc[o];  bf[o] = (b1-mean)*sc + beta;
//     w2t[o][g][k] = w2[g*49+k][o]  (k<49; pad 49..63 with 0)
// ---------------------------------------------------------------------------
extern "C" __global__ void __launch_bounds__(256)
k0_prep(const float* __restrict__ w1, const float* __restrict__ b1,
        const float* __restrict__ gamma, const float* __restrict__ beta,
        const float* __restrict__ mean,  const float* __restrict__ var,
        const float* __restrict__ w2,
        float* __restrict__ w1f, float* __restrict__ bf, float* __restrict__ w2t)
{
    const int id = blockIdx.x * 256 + threadIdx.x;           // 0 .. 65535
    if (id < Cc * Cr) {
        const int c = id / Cr, o = id - c * Cr;
        const float sc = gamma[o] * rsqrtf(var[o] + 1e-5f);
        w1f[id] = w1[o * Cc + c] * sc;
        if (id < Cr)
            bf[id] = fmaf(b1[id] - mean[id], gamma[id] * rsqrtf(var[id] + 1e-5f),
                          beta[id]);
    }
    if (id < Cr * Gg * 64) {
        const int o = id / (Gg * 64);
        const int r = id - o * (Gg * 64);
        const int g = r / 64, k = r - g * 64;
        w2t[id] = (k < KK) ? w2[(g * KK + k) * Cr + o] : 0.f;
    }
}

// ---------------------------------------------------------------------------
// k1: 1x1 conv + folded BN + ReLU.
// grid (196, 2) x 256. lane = px; wave wv covers o = by*32 + wv*8 .. +8.
// Per c-step: 1 coalesced x load + dwordx8 s_load of w1f[c][o0..] + 8 FMA.
// x read twice total (25.6 MB). t layout [64][12544].
// ---------------------------------------------------------------------------
extern "C" __global__ void __launch_bounds__(256)
k1_conv_bn_relu(const float* __restrict__ x, const float* __restrict__ w1f,
                const float* __restrict__ bf, float* __restrict__ t)
{
    const int lane = threadIdx.x & 63;
    const int wv   = __builtin_amdgcn_readfirstlane(threadIdx.x >> 6);  // 0..3
    const int px   = blockIdx.x * 64 + lane;                 // exact: 196*64=12544
    const int o0   = __builtin_amdgcn_readfirstlane((int)blockIdx.y * 32 + wv * 8);

    const int n  = px / HW;
    const int hw = px - n * HW;
    const float* xb = x + (size_t)n * Cc * HW + hw;

    float acc[8];
#pragma unroll
    for (int i = 0; i < 8; ++i) acc[i] = 0.f;

    float xv = xb[0];
#pragma unroll 4
    for (int c = 0; c < Cc; ++c) {
        const float xcur = xv;
        if (c < Cc - 1) xv = xb[(size_t)(c + 1) * HW];       // 1-deep prefetch
        const float* wr = w1f + c * Cr + o0;                 // uniform -> s_load x8
#pragma unroll
        for (int i = 0; i < 8; ++i)
            acc[i] = fmaf(xcur, wr[i], acc[i]);
    }

#pragma unroll
    for (int i = 0; i < 8; ++i) {
        const float v = acc[i] + bf[o0 + i];
        t[(size_t)(o0 + i) * NPX + px] = v > 0.f ? v : 0.f;  // coalesced store
    }
}

// ---------------------------------------------------------------------------
// k2: fused kernel-gen + involution.
// grid (196 px-tiles, 4) x 256. wave wv -> group g = by*4+wv; lane -> px.
// Phase A: ker[49] per lane, streamed: for o: tv=t[o][px] (coalesced),
//          wr = w2t[o][g][0..48] (contiguous uniform -> s_load_dwordx16 x3),
//          ker[k] += tv*wr[k].
// Phase B: acc[16] over taps; per tap one cndmask (kv = ok ? ker[k] : 0),
//          clamped address, 16 coalesced x loads.
// No LDS, no barriers; px-tile of 64 => all lanes always active.
// ---------------------------------------------------------------------------
extern "C" __global__ void __launch_bounds__(256)
k2_involution(const float* __restrict__ x, const float* __restrict__ t,
              const float* __restrict__ w2t, const float* __restrict__ b2,
              float* __restrict__ out)
{
    const int lane = threadIdx.x & 63;
    const int wv   = __builtin_amdgcn_readfirstlane(threadIdx.x >> 6);  // 0..3
    const int pxt  = blockIdx.x;                             // 0..195
    const int g    = __builtin_amdgcn_readfirstlane((int)blockIdx.y * 4 + wv);
    const int px   = pxt * 64 + lane;
    const int n    = __builtin_amdgcn_readfirstlane(pxt / 49);  // 3136/64=49 tiles/img
    const int hw   = px - n * HW;                            // lane-contiguous
    const int h    = hw / Ww;                                // per-lane
    const int w    = hw - h * Ww;

    // ---- Phase A: ker[k] = b2[g*49+k] + sum_o t[o][px] * w2t[o][g][k] ----
    float ker[KK];
    const float* b2g = b2 + g * KK;                          // uniform s_loads
#pragma unroll
    for (int k = 0; k < KK; ++k) ker[k] = b2g[k];

    const float* tp = t + px;
    const float* wt = w2t + g * 64;                          // + o*1024, 256B-aligned

    float tv = tp[0];
    for (int o = 0; o < Cr; ++o) {
        const float tcur = tv;
        if (o < Cr - 1) tv = tp[(size_t)(o + 1) * NPX];      // 1-deep prefetch
        const float* wr = wt + o * (Gg * 64);                // uniform -> s_load x16
#pragma unroll
        for (int k = 0; k < KK; ++k)
            ker[k] = fmaf(tcur, wr[k], ker[k]);
    }

    // ---- Phase B: involution gather ----
    float acc[16];
#pragma unroll
    for (int i = 0; i < 16; ++i) acc[i] = 0.f;

    const float* xg = x + (size_t)n * Cc * HW + (size_t)(g * 16) * HW;

#pragma unroll
    for (int kh = 0; kh < 7; ++kh) {
        const int hh = h + kh - 3;                           // per-lane
#pragma unroll
        for (int kw = 0; kw < 7; ++kw) {
            const int ww = w + kw - 3;
            const bool ok = (hh >= 0) & (hh < Hh) & (ww >= 0) & (ww < Ww);
            const float kv  = ok ? ker[kh * 7 + kw] : 0.f;   // one cndmask
            const int  off  = ok ? hh * Ww + ww : 0;         // safe clamped addr
            const float* xr = xg + off;
#pragma unroll
            for (int c = 0; c < 16; ++c)
                acc[c] = fmaf(xr[(size_t)c * HW], kv, acc[c]);
        }
    }

    // ---- store: out[n][g*16+c][hw] ----
    float* og = out + (size_t)n * Cc * HW + (size_t)(g * 16) * HW + hw;
#pragma unroll
    for (int c = 0; c < 16; ++c)
        og[(size_t)c * HW] = acc[c];                         // coalesced per c
}

// ---------------------------------------------------------------------------
extern "C" void kernel_launch(void* const* d_in, const int* in_sizes, int n_in,
                              void* d_out, int out_size, void* d_ws, size_t ws_size,
                              hipStream_t stream)
{
    const float* x     = (const float*)d_in[0];
    const float* w1    = (const float*)d_in[1];
    const float* b1    = (const float*)d_in[2];
    const float* gamma = (const float*)d_in[3];
    const float* beta  = (const float*)d_in[4];
    const float* mean  = (const float*)d_in[5];
    const float* var   = (const float*)d_in[6];
    const float* w2    = (const float*)d_in[7];
    const float* b2    = (const float*)d_in[8];

    float* ws  = (float*)d_ws;        // ~3.5 MB total
    float* w1f = ws + WS_W1F;
    float* bf  = ws + WS_BF;
    float* w2t = ws + WS_W2T;
    float* t   = ws + WS_T;
    float* out = (float*)d_out;

    k0_prep<<<dim3((Cr * Gg * 64) / 256), 256, 0, stream>>>(
        w1, b1, gamma, beta, mean, var, w2, w1f, bf, w2t);
    k1_conv_bn_relu<<<dim3(NPX / 64, 2), 256, 0, stream>>>(x, w1f, bf, t);
    k2_involution<<<dim3(NPX / 64, 4), 256, 0, stream>>>(x, t, w2t, b2, out);
}

// Round 6
// 538.218 us; speedup vs baseline: 1.1975x; 1.1975x over previous
//
#include <hip/hip_runtime.h>

// Involution (RedNet-style), N=4 C=256 H=W=56, K=7, G=16, ratio=4 (Cr=64).
// k0: fold BN into w1f/bf; transpose w2 -> w2t[o][g][64] (padded rows).
// k1: conv1 GEMM  t[o][px] = relu(<x[:,px], w1f[:,o]> + bf[o]).
//     8-deep manual load batching, #pragma unroll 1 on the c loop.
// k2: fused kernel-gen + involution, ker chunked 13/13/13/10:
//     per chunk: ker[j] = b2 + sum_o t[o,px]*w2t[o][g][k]  (uniform w rows),
//     then gather chunk's taps from x into acc[16]. Bounded unrolling.

namespace {
constexpr int Nn  = 4;
constexpr int Cc  = 256;
constexpr int Hh  = 56;
constexpr int Ww  = 56;
constexpr int HW  = Hh * Ww;        // 3136
constexpr int NPX = Nn * HW;        // 12544
constexpr int KK  = 49;             // 7x7
constexpr int Cr  = 64;             // reduced channels
constexpr int Gg  = 16;             // groups
constexpr int WROW = Gg * 64;       // w2t o-row stride (1024 floats)

// workspace layout (floats)
constexpr int WS_W1F = 0;                     // [256][64]    16384
constexpr int WS_BF  = WS_W1F + Cc * Cr;      // [64]
constexpr int WS_W2T = WS_BF + Cr;            // [64][16][64] 65536
constexpr int WS_T   = WS_W2T + Cr * WROW;    // [64][12544]
}

// ---------------------------------------------------------------------------
// k0: weight prep.
// ---------------------------------------------------------------------------
extern "C" __global__ void __launch_bounds__(256)
k0_prep(const float* __restrict__ w1, const float* __restrict__ b1,
        const float* __restrict__ gamma, const float* __restrict__ beta,
        const float* __restrict__ mean,  const float* __restrict__ var,
        const float* __restrict__ w2,
        float* __restrict__ w1f, float* __restrict__ bf, float* __restrict__ w2t)
{
    const int id = blockIdx.x * 256 + threadIdx.x;           // 0 .. 65535
    if (id < Cc * Cr) {
        const int c = id / Cr, o = id - c * Cr;
        const float sc = gamma[o] * rsqrtf(var[o] + 1e-5f);
        w1f[id] = w1[o * Cc + c] * sc;
        if (id < Cr)
            bf[id] = fmaf(b1[id] - mean[id], gamma[id] * rsqrtf(var[id] + 1e-5f),
                          beta[id]);
    }
    if (id < Cr * WROW) {
        const int o = id / WROW;
        const int r = id - o * WROW;
        const int g = r / 64, k = r - g * 64;
        w2t[id] = (k < KK) ? w2[(g * KK + k) * Cr + o] : 0.f;
    }
}

// ---------------------------------------------------------------------------
// k1: 1x1 conv + folded BN + ReLU.
// grid (196, 2) x 256. lane = px; wave wv covers o = by*32 + wv*8 .. +8.
// c loop: unroll 1, manual 8-wide x batch (8 outstanding loads).
// ---------------------------------------------------------------------------
extern "C" __global__ void __launch_bounds__(256)
k1_conv_bn_relu(const float* __restrict__ x, const float* __restrict__ w1f,
                const float* __restrict__ bf, float* __restrict__ t)
{
    const int lane = threadIdx.x & 63;
    const int wv   = __builtin_amdgcn_readfirstlane(threadIdx.x >> 6);  // 0..3
    const int px   = blockIdx.x * 64 + lane;                 // exact: 196*64=12544
    const int o0   = __builtin_amdgcn_readfirstlane((int)blockIdx.y * 32 + wv * 8);

    const int n  = px / HW;
    const int hw = px - n * HW;
    const float* xb = x + (size_t)n * Cc * HW + hw;

    float acc[8];
#pragma unroll
    for (int i = 0; i < 8; ++i) acc[i] = 0.f;

    float xv[8];
#pragma unroll
    for (int i = 0; i < 8; ++i) xv[i] = xb[(size_t)i * HW];  // coalesced batch

#pragma unroll 1
    for (int c0 = 0; c0 < Cc; c0 += 8) {
        float xn[8];
        const bool more = (c0 + 8) < Cc;
        if (more) {
#pragma unroll
            for (int i = 0; i < 8; ++i)
                xn[i] = xb[(size_t)(c0 + 8 + i) * HW];       // prefetch batch
        }
#pragma unroll
        for (int cc = 0; cc < 8; ++cc) {
            const float* wr = w1f + (c0 + cc) * Cr + o0;     // uniform row
#pragma unroll
            for (int i = 0; i < 8; ++i)
                acc[i] = fmaf(xv[cc], wr[i], acc[i]);
        }
        if (more) {
#pragma unroll
            for (int i = 0; i < 8; ++i) xv[i] = xn[i];
        }
    }

#pragma unroll
    for (int i = 0; i < 8; ++i) {
        const float v = acc[i] + bf[o0 + i];
        t[(size_t)(o0 + i) * NPX + px] = v > 0.f ? v : 0.f;  // coalesced store
    }
}

// ---------------------------------------------------------------------------
// k2 chunk helper: taps [K0, K0+KN).  Phase A streams t (4-wide batches,
// o-loop unroll 1) against uniform w2t rows; Phase B gathers x.
// ---------------------------------------------------------------------------
template<int K0, int KN>
__device__ __forceinline__ void
do_chunk(const float* __restrict__ tp, const float* __restrict__ wg,
         const float* __restrict__ b2g, const float* __restrict__ xg,
         int h, int w, float (&acc)[16])
{
    float ker[KN];
#pragma unroll
    for (int j = 0; j < KN; ++j) ker[j] = b2g[K0 + j];       // uniform

#pragma unroll 1
    for (int o = 0; o < Cr; o += 4) {
        const float tv0 = tp[(size_t)(o + 0) * NPX];         // coalesced batch
        const float tv1 = tp[(size_t)(o + 1) * NPX];
        const float tv2 = tp[(size_t)(o + 2) * NPX];
        const float tv3 = tp[(size_t)(o + 3) * NPX];
        const float* w0 = wg + (o + 0) * WROW + K0;          // uniform rows
        const float* w1r = wg + (o + 1) * WROW + K0;
        const float* w2r = wg + (o + 2) * WROW + K0;
        const float* w3r = wg + (o + 3) * WROW + K0;
#pragma unroll
        for (int j = 0; j < KN; ++j) ker[j] = fmaf(tv0, w0[j],  ker[j]);
#pragma unroll
        for (int j = 0; j < KN; ++j) ker[j] = fmaf(tv1, w1r[j], ker[j]);
#pragma unroll
        for (int j = 0; j < KN; ++j) ker[j] = fmaf(tv2, w2r[j], ker[j]);
#pragma unroll
        for (int j = 0; j < KN; ++j) ker[j] = fmaf(tv3, w3r[j], ker[j]);
    }

#pragma unroll
    for (int j = 0; j < KN; ++j) {
        const int k  = K0 + j;
        const int kh = k / 7;
        const int kw = k - kh * 7;
        const int hh = h + kh - 3;                           // per-lane
        const int ww = w + kw - 3;
        const bool ok = (hh >= 0) & (hh < Hh) & (ww >= 0) & (ww < Ww);
        const float kv = ok ? ker[j] : 0.f;                  // one cndmask
        const int  off = ok ? hh * Ww + ww : 0;              // safe clamped addr
        const float* xr = xg + off;
#pragma unroll
        for (int c = 0; c < 16; ++c)
            acc[c] = fmaf(xr[(size_t)c * HW], kv, acc[c]);
    }
}

// ---------------------------------------------------------------------------
// k2: fused kernel-gen + involution.
// grid (196 px-tiles, 4) x 256. wave wv -> group g = by*4+wv; lane -> px.
// ---------------------------------------------------------------------------
extern "C" __global__ void __launch_bounds__(256)
k2_involution(const float* __restrict__ x, const float* __restrict__ t,
              const float* __restrict__ w2t, const float* __restrict__ b2,
              float* __restrict__ out)
{
    const int lane = threadIdx.x & 63;
    const int wv   = __builtin_amdgcn_readfirstlane(threadIdx.x >> 6);  // 0..3
    const int pxt  = blockIdx.x;                             // 0..195
    const int g    = __builtin_amdgcn_readfirstlane((int)blockIdx.y * 4 + wv);
    const int px   = pxt * 64 + lane;
    const int n    = __builtin_amdgcn_readfirstlane(pxt / 49);  // 49 tiles/image
    const int hw   = px - n * HW;
    const int h    = hw / Ww;                                // per-lane
    const int w    = hw - h * Ww;

    const float* tp  = t + px;
    const float* wg  = w2t + g * 64;
    const float* b2g = b2 + g * KK;
    const float* xg  = x + (size_t)n * Cc * HW + (size_t)(g * 16) * HW;

    float acc[16];
#pragma unroll
    for (int i = 0; i < 16; ++i) acc[i] = 0.f;

    do_chunk< 0, 13>(tp, wg, b2g, xg, h, w, acc);
    do_chunk<13, 13>(tp, wg, b2g, xg, h, w, acc);
    do_chunk<26, 13>(tp, wg, b2g, xg, h, w, acc);
    do_chunk<39, 10>(tp, wg, b2g, xg, h, w, acc);

    float* og = out + (size_t)n * Cc * HW + (size_t)(g * 16) * HW + hw;
#pragma unroll
    for (int c = 0; c < 16; ++c)
        og[(size_t)c * HW] = acc[c];                         // coalesced per c
}

// ---------------------------------------------------------------------------
extern "C" void kernel_launch(void* const* d_in, const int* in_sizes, int n_in,
                              void* d_out, int out_size, void* d_ws, size_t ws_size,
                              hipStream_t stream)
{
    const float* x     = (const float*)d_in[0];
    const float* w1    = (const float*)d_in[1];
    const float* b1    = (const float*)d_in[2];
    const float* gamma = (const float*)d_in[3];
    const float* beta  = (const float*)d_in[4];
    const float* mean  = (const float*)d_in[5];
    const float* var   = (const float*)d_in[6];
    const float* w2    = (const float*)d_in[7];
    const float* b2    = (const float*)d_in[8];

    float* ws  = (float*)d_ws;        // ~3.5 MB total
    float* w1f = ws + WS_W1F;
    float* bf  = ws + WS_BF;
    float* w2t = ws + WS_W2T;
    float* t   = ws + WS_T;
    float* out = (float*)d_out;

    k0_prep<<<dim3(256), 256, 0, stream>>>(
        w1, b1, gamma, beta, mean, var, w2, w1f, bf, w2t);
    k1_conv_bn_relu<<<dim3(NPX / 64, 2), 256, 0, stream>>>(x, w1f, bf, t);
    k2_involution<<<dim3(NPX / 64, 4), 256, 0, stream>>>(x, t, w2t, b2, out);
}

// Round 7
// 452.344 us; speedup vs baseline: 1.4248x; 1.1898x over previous
//
#include <hip/hip_runtime.h>

// Involution (RedNet-style), N=4 C=256 H=W=56, K=7, G=16, ratio=4 (Cr=64).
// k0: fold BN into w1f/bf; transpose w2 -> w2t[o][g][64] (padded rows).
// kT: transpose x -> xT[n][hw][c] (channel-last) for the tap gather.
// k1: conv1 GEMM, weights via constant-address-space s_loads (0 VGPR).
// k2: per-lane ker[49] streamed from t against SGPR weight rows, then
//     tap gather as 4x dwordx4 from xT. launch_bounds(256,4) caps VGPR=128.

#define CONST_AS __attribute__((address_space(4)))

namespace {
constexpr int Nn  = 4;
constexpr int Cc  = 256;
constexpr int Hh  = 56;
constexpr int Ww  = 56;
constexpr int HW  = Hh * Ww;        // 3136
constexpr int NPX = Nn * HW;        // 12544
constexpr int KK  = 49;             // 7x7
constexpr int Cr  = 64;             // reduced channels
constexpr int Gg  = 16;             // groups
constexpr int WROW = Gg * 64;       // w2t o-row stride (1024 floats)

// workspace layout (floats)
constexpr size_t WS_W1F = 0;                          // [256][64]
constexpr size_t WS_BF  = WS_W1F + (size_t)Cc * Cr;   // [64]
constexpr size_t WS_W2T = WS_BF  + Cr;                // [64][16][64]
constexpr size_t WS_T   = WS_W2T + (size_t)Cr * WROW; // [64][12544]
constexpr size_t WS_XT  = WS_T   + (size_t)Cr * NPX;  // [4][3136][256]
constexpr size_t WS_END = WS_XT  + (size_t)Nn * HW * Cc;

// CK-style cast to constant address space: uniform loads become s_load_*.
__device__ __forceinline__ const CONST_AS float* cptr(const float* p) {
    return (const CONST_AS float*)(unsigned long long)p;
}
}

// ---------------------------------------------------------------------------
// k0: weight prep.
// ---------------------------------------------------------------------------
__global__ void __launch_bounds__(256)
k0_prep(const float* __restrict__ w1, const float* __restrict__ b1,
        const float* __restrict__ gamma, const float* __restrict__ beta,
        const float* __restrict__ mean,  const float* __restrict__ var,
        const float* __restrict__ w2,
        float* __restrict__ w1f, float* __restrict__ bf, float* __restrict__ w2t)
{
    const int id = blockIdx.x * 256 + threadIdx.x;           // 0 .. 65535
    if (id < Cc * Cr) {
        const int c = id / Cr, o = id - c * Cr;
        const float sc = gamma[o] * rsqrtf(var[o] + 1e-5f);
        w1f[id] = w1[o * Cc + c] * sc;
        if (id < Cr)
            bf[id] = fmaf(b1[id] - mean[id], gamma[id] * rsqrtf(var[id] + 1e-5f),
                          beta[id]);
    }
    if (id < Cr * WROW) {
        const int o = id / WROW;
        const int r = id - o * WROW;
        const int g = r / 64, k = r - g * 64;
        w2t[id] = (k < KK) ? w2[(g * KK + k) * Cr + o] : 0.f;
    }
}

// ---------------------------------------------------------------------------
// kT: x[n][c][hw] -> xT[n][hw][c].  784 blocks: 64x64 LDS tile, padded.
// ---------------------------------------------------------------------------
__global__ void __launch_bounds__(256)
kT_transpose(const float* __restrict__ x, float* __restrict__ xT)
{
    __shared__ float tile[64][65];
    const int b   = blockIdx.x;            // n*196 + ct*49 + hwt
    const int hwt = b % 49;
    const int ct  = (b / 49) & 3;
    const int n   = b / 196;
    const int l   = threadIdx.x & 63;
    const int q   = threadIdx.x >> 6;      // 0..3

    const float* xb = x + ((size_t)n * Cc + ct * 64) * HW + hwt * 64;
#pragma unroll
    for (int i = 0; i < 16; ++i)
        tile[q * 16 + i][l] = xb[(size_t)(q * 16 + i) * HW + l];  // coalesced
    __syncthreads();

    float* xo = xT + ((size_t)n * HW + hwt * 64) * Cc + ct * 64;
#pragma unroll
    for (int i = 0; i < 16; ++i)
        xo[(size_t)(q * 16 + i) * Cc + l] = tile[l][q * 16 + i];  // coalesced
}

// ---------------------------------------------------------------------------
// k1: 1x1 conv + folded BN + ReLU.
// grid (196, 2) x 256. lane = px; wave wv covers o = by*32 + wv*8 .. +8.
// Weights via AS(4) -> s_load_dwordx8 per c (SGPRs, SMEM pipe).
// ---------------------------------------------------------------------------
__global__ void __launch_bounds__(256, 4)
k1_conv_bn_relu(const float* __restrict__ x, const float* __restrict__ w1f,
                const float* __restrict__ bf, float* __restrict__ t)
{
    const int lane = threadIdx.x & 63;
    const int wv   = __builtin_amdgcn_readfirstlane(threadIdx.x >> 6);  // 0..3
    const int px   = blockIdx.x * 64 + lane;                 // exact: 196*64=12544
    const int o0   = __builtin_amdgcn_readfirstlane((int)blockIdx.y * 32 + wv * 8);

    const int n  = px / HW;
    const int hw = px - n * HW;
    const float* xb = x + (size_t)n * Cc * HW + hw;
    const CONST_AS float* wf = cptr(w1f) + o0;

    float acc[8];
#pragma unroll
    for (int i = 0; i < 8; ++i) acc[i] = 0.f;

    float xv[8];
#pragma unroll
    for (int i = 0; i < 8; ++i) xv[i] = xb[(size_t)i * HW];  // coalesced batch

#pragma unroll 1
    for (int c0 = 0; c0 < Cc; c0 += 8) {
        float xn[8];
#pragma unroll
        for (int i = 0; i < 8; ++i)                           // prefetch (wraps @end)
            xn[i] = xb[(size_t)((c0 + 8 + i) & (Cc - 1)) * HW];
#pragma unroll
        for (int cc = 0; cc < 8; ++cc) {
            const CONST_AS float* wr = wf + (c0 + cc) * Cr;   // uniform -> s_load x8
#pragma unroll
            for (int i = 0; i < 8; ++i)
                acc[i] = fmaf(xv[cc], wr[i], acc[i]);
        }
#pragma unroll
        for (int i = 0; i < 8; ++i) xv[i] = xn[i];
    }

#pragma unroll
    for (int i = 0; i < 8; ++i) {
        const float v = acc[i] + bf[o0 + i];
        t[(size_t)(o0 + i) * NPX + px] = v > 0.f ? v : 0.f;  // coalesced store
    }
}

// ---------------------------------------------------------------------------
// k2: fused kernel-gen + involution.
// grid (196, 4) x 256; wave wv -> group g = by*4+wv; lane -> px.
// Phase A: ker[49] per lane; per o: 1 coalesced t load + one 49-float SGPR
//          weight row (s_load_dwordx16 x3) + 49 FMA.
// Phase B (XT=1): per tap: 4x global_load_dwordx4 from xT + 16 FMA,
//          sched_barrier(0) per tap to bound in-flight loads.
// ---------------------------------------------------------------------------
template<int USE_XT>
__global__ void __launch_bounds__(256, 4)
k2_involution(const float* __restrict__ x, const float* __restrict__ xT,
              const float* __restrict__ t, const float* __restrict__ w2t,
              const float* __restrict__ b2, float* __restrict__ out)
{
    const int lane = threadIdx.x & 63;
    const int wv   = __builtin_amdgcn_readfirstlane(threadIdx.x >> 6);  // 0..3
    const int pxt  = blockIdx.x;                             // 0..195
    const int g    = __builtin_amdgcn_readfirstlane((int)blockIdx.y * 4 + wv);
    const int px   = pxt * 64 + lane;
    const int n    = __builtin_amdgcn_readfirstlane(pxt / 49);  // 49 tiles/image
    const int hw   = px - n * HW;
    const int h    = hw / Ww;                                // per-lane
    const int w    = hw - h * Ww;

    const float* tp = t + px;
    const CONST_AS float* wg  = cptr(w2t) + g * 64;
    const CONST_AS float* b2g = cptr(b2) + g * KK;

    // ---- Phase A ----
    float ker[KK];
#pragma unroll
    for (int j = 0; j < KK; ++j) ker[j] = b2g[j];            // SGPR init

    float tv = tp[0];
#pragma unroll 1
    for (int o = 0; o < Cr; ++o) {
        const float tc = tv;
        tv = tp[(size_t)((o + 1) & (Cr - 1)) * NPX];         // 1-deep prefetch
        const CONST_AS float* wr = wg + o * WROW;            // s_load_dwordx16 x3
#pragma unroll
        for (int j = 0; j < KK; ++j)
            ker[j] = fmaf(tc, wr[j], ker[j]);                // SGPR operand
    }

    // ---- Phase B ----
    float acc[16];
#pragma unroll
    for (int i = 0; i < 16; ++i) acc[i] = 0.f;

    if (USE_XT) {
        const float* xTg = xT + (size_t)n * HW * Cc + g * 16;
#pragma unroll
        for (int kh = 0; kh < 7; ++kh) {
            const int hh = h + kh - 3;
#pragma unroll
            for (int kw = 0; kw < 7; ++kw) {
                const int j  = kh * 7 + kw;
                const int ww = w + kw - 3;
                const bool ok = (hh >= 0) & (hh < Hh) & (ww >= 0) & (ww < Ww);
                const float kv = ok ? ker[j] : 0.f;
                const int  off = ok ? hh * Ww + ww : 0;
                const float4* pv = (const float4*)(xTg + (size_t)off * Cc);
                const float4 v0 = pv[0], v1 = pv[1], v2 = pv[2], v3 = pv[3];
                acc[ 0] = fmaf(v0.x, kv, acc[ 0]);
                acc[ 1] = fmaf(v0.y, kv, acc[ 1]);
                acc[ 2] = fmaf(v0.z, kv, acc[ 2]);
                acc[ 3] = fmaf(v0.w, kv, acc[ 3]);
                acc[ 4] = fmaf(v1.x, kv, acc[ 4]);
                acc[ 5] = fmaf(v1.y, kv, acc[ 5]);
                acc[ 6] = fmaf(v1.z, kv, acc[ 6]);
                acc[ 7] = fmaf(v1.w, kv, acc[ 7]);
                acc[ 8] = fmaf(v2.x, kv, acc[ 8]);
                acc[ 9] = fmaf(v2.y, kv, acc[ 9]);
                acc[10] = fmaf(v2.z, kv, acc[10]);
                acc[11] = fmaf(v2.w, kv, acc[11]);
                acc[12] = fmaf(v3.x, kv, acc[12]);
                acc[13] = fmaf(v3.y, kv, acc[13]);
                acc[14] = fmaf(v3.z, kv, acc[14]);
                acc[15] = fmaf(v3.w, kv, acc[15]);
                __builtin_amdgcn_sched_barrier(0);           // bound in-flight loads
            }
        }
    } else {
        const float* xg = x + (size_t)n * Cc * HW + (size_t)(g * 16) * HW;
#pragma unroll
        for (int kh = 0; kh < 7; ++kh) {
            const int hh = h + kh - 3;
#pragma unroll
            for (int kw = 0; kw < 7; ++kw) {
                const int j  = kh * 7 + kw;
                const int ww = w + kw - 3;
                const bool ok = (hh >= 0) & (hh < Hh) & (ww >= 0) & (ww < Ww);
                const float kv = ok ? ker[j] : 0.f;
                const int  off = ok ? hh * Ww + ww : 0;
                const float* xr = xg + off;
#pragma unroll
                for (int c = 0; c < 16; ++c)
                    acc[c] = fmaf(xr[(size_t)c * HW], kv, acc[c]);
                __builtin_amdgcn_sched_barrier(0);
            }
        }
    }

    // ---- store: out[n][g*16+c][hw] ----
    float* og = out + (size_t)n * Cc * HW + (size_t)(g * 16) * HW + hw;
#pragma unroll
    for (int c = 0; c < 16; ++c)
        og[(size_t)c * HW] = acc[c];                         // coalesced per c
}

// ---------------------------------------------------------------------------
extern "C" void kernel_launch(void* const* d_in, const int* in_sizes, int n_in,
                              void* d_out, int out_size, void* d_ws, size_t ws_size,
                              hipStream_t stream)
{
    const float* x     = (const float*)d_in[0];
    const float* w1    = (const float*)d_in[1];
    const float* b1    = (const float*)d_in[2];
    const float* gamma = (const float*)d_in[3];
    const float* beta  = (const float*)d_in[4];
    const float* mean  = (const float*)d_in[5];
    const float* var   = (const float*)d_in[6];
    const float* w2    = (const float*)d_in[7];
    const float* b2    = (const float*)d_in[8];

    float* ws  = (float*)d_ws;
    float* w1f = ws + WS_W1F;
    float* bf  = ws + WS_BF;
    float* w2t = ws + WS_W2T;
    float* t   = ws + WS_T;
    float* xT  = ws + WS_XT;
    float* out = (float*)d_out;

    const bool use_xt = ws_size >= WS_END * sizeof(float);   // ~16.4 MB

    k0_prep<<<dim3(256), 256, 0, stream>>>(
        w1, b1, gamma, beta, mean, var, w2, w1f, bf, w2t);
    k1_conv_bn_relu<<<dim3(NPX / 64, 2), 256, 0, stream>>>(x, w1f, bf, t);
    if (use_xt) {
        kT_transpose<<<dim3(Nn * 196), 256, 0, stream>>>(x, xT);
        k2_involution<1><<<dim3(NPX / 64, 4), 256, 0, stream>>>(
            x, xT, t, w2t, b2, out);
    } else {
        k2_involution<0><<<dim3(NPX / 64, 4), 256, 0, stream>>>(
            x, nullptr, t, w2t, b2, out);
    }
}

// Round 8
// 354.651 us; speedup vs baseline: 1.8173x; 1.2755x over previous
//
#include <hip/hip_runtime.h>

// Involution (RedNet-style), N=4 C=256 H=W=56, K=7, G=16, ratio=4 (Cr=64).
// k0: fold BN into w1f/bf; transpose w2 -> w2t[o][g][64] (padded rows).
// k1: conv1 GEMM, weights via constant-address-space s_loads.
// k2: per-lane ker chunked 25/24, streamed from t against SGPR weight rows,
//     NCHW coalesced tap gather. amdgpu_waves_per_eu(4,4) pins the register
//     budget at 128 VGPR so nothing spills.

#define CONST_AS __attribute__((address_space(4)))

namespace {
constexpr int Nn  = 4;
constexpr int Cc  = 256;
constexpr int Hh  = 56;
constexpr int Ww  = 56;
constexpr int HW  = Hh * Ww;        // 3136
constexpr int NPX = Nn * HW;        // 12544
constexpr int KK  = 49;             // 7x7
constexpr int Cr  = 64;             // reduced channels
constexpr int Gg  = 16;             // groups
constexpr int WROW = Gg * 64;       // w2t o-row stride (1024 floats)

// workspace layout (floats)
constexpr size_t WS_W1F = 0;                          // [256][64]
constexpr size_t WS_BF  = WS_W1F + (size_t)Cc * Cr;   // [64]
constexpr size_t WS_W2T = WS_BF  + Cr;                // [64][16][64]
constexpr size_t WS_T   = WS_W2T + (size_t)Cr * WROW; // [64][12544]

// CK-style cast to constant address space: uniform loads become s_load_*.
__device__ __forceinline__ const CONST_AS float* cptr(const float* p) {
    return (const CONST_AS float*)(unsigned long long)p;
}
}

// ---------------------------------------------------------------------------
// k0: weight prep.
// ---------------------------------------------------------------------------
__global__ void __launch_bounds__(256)
k0_prep(const float* __restrict__ w1, const float* __restrict__ b1,
        const float* __restrict__ gamma, const float* __restrict__ beta,
        const float* __restrict__ mean,  const float* __restrict__ var,
        const float* __restrict__ w2,
        float* __restrict__ w1f, float* __restrict__ bf, float* __restrict__ w2t)
{
    const int id = blockIdx.x * 256 + threadIdx.x;           // 0 .. 65535
    if (id < Cc * Cr) {
        const int c = id / Cr, o = id - c * Cr;
        const float sc = gamma[o] * rsqrtf(var[o] + 1e-5f);
        w1f[id] = w1[o * Cc + c] * sc;
        if (id < Cr)
            bf[id] = fmaf(b1[id] - mean[id], gamma[id] * rsqrtf(var[id] + 1e-5f),
                          beta[id]);
    }
    if (id < Cr * WROW) {
        const int o = id / WROW;
        const int r = id - o * WROW;
        const int g = r / 64, k = r - g * 64;
        w2t[id] = (k < KK) ? w2[(g * KK + k) * Cr + o] : 0.f;
    }
}

// ---------------------------------------------------------------------------
// k1: 1x1 conv + folded BN + ReLU.
// grid (196, 2) x 256. lane = px; wave wv covers o = by*32 + wv*8 .. +8.
// Weights via AS(4) -> s_load_dwordx8 per c (SGPRs, SMEM pipe).
// ---------------------------------------------------------------------------
__global__ void __launch_bounds__(256)
k1_conv_bn_relu(const float* __restrict__ x, const float* __restrict__ w1f,
                const float* __restrict__ bf, float* __restrict__ t)
{
    const int lane = threadIdx.x & 63;
    const int wv   = __builtin_amdgcn_readfirstlane(threadIdx.x >> 6);  // 0..3
    const int px   = blockIdx.x * 64 + lane;                 // exact: 196*64=12544
    const int o0   = __builtin_amdgcn_readfirstlane((int)blockIdx.y * 32 + wv * 8);

    const int n  = px / HW;
    const int hw = px - n * HW;
    const float* xb = x + (size_t)n * Cc * HW + hw;
    const CONST_AS float* wf = cptr(w1f) + o0;

    float acc[8];
#pragma unroll
    for (int i = 0; i < 8; ++i) acc[i] = 0.f;

    float xv[8];
#pragma unroll
    for (int i = 0; i < 8; ++i) xv[i] = xb[(size_t)i * HW];  // coalesced batch

#pragma unroll 1
    for (int c0 = 0; c0 < Cc; c0 += 8) {
        float xn[8];
#pragma unroll
        for (int i = 0; i < 8; ++i)                           // prefetch (wraps @end)
            xn[i] = xb[(size_t)((c0 + 8 + i) & (Cc - 1)) * HW];
#pragma unroll
        for (int cc = 0; cc < 8; ++cc) {
            const CONST_AS float* wr = wf + (c0 + cc) * Cr;   // uniform -> s_load x8
#pragma unroll
            for (int i = 0; i < 8; ++i)
                acc[i] = fmaf(xv[cc], wr[i], acc[i]);
        }
#pragma unroll
        for (int i = 0; i < 8; ++i) xv[i] = xn[i];
    }

#pragma unroll
    for (int i = 0; i < 8; ++i) {
        const float v = acc[i] + bf[o0 + i];
        t[(size_t)(o0 + i) * NPX + px] = v > 0.f ? v : 0.f;  // coalesced store
    }
}

// ---------------------------------------------------------------------------
// k2 chunk: taps [K0, K0+KN). Phase A: ker[KN] streamed from t (1-deep
// prefetch, unroll 1) against SGPR weight rows. Phase B: NCHW coalesced
// gather, 16 FMA/tap, sched_barrier bounds load clustering.
// ---------------------------------------------------------------------------
template<int K0, int KN>
__device__ __forceinline__ void
do_chunk(const float* __restrict__ tp, const CONST_AS float* __restrict__ wg,
         const CONST_AS float* __restrict__ b2g, const float* __restrict__ xg,
         int h, int w, float (&acc)[16])
{
    float ker[KN];
#pragma unroll
    for (int j = 0; j < KN; ++j) ker[j] = b2g[K0 + j];       // SGPR init

    float tv = tp[0];
#pragma unroll 1
    for (int o = 0; o < Cr; ++o) {
        const float tc = tv;
        tv = tp[(size_t)((o + 1) & (Cr - 1)) * NPX];         // 1-deep prefetch
        const CONST_AS float* wr = wg + o * WROW + K0;       // s_load_dwordx16
#pragma unroll
        for (int j = 0; j < KN; ++j)
            ker[j] = fmaf(tc, wr[j], ker[j]);                // SGPR operand
    }

#pragma unroll
    for (int j = 0; j < KN; ++j) {
        const int k  = K0 + j;
        const int kh = k / 7;
        const int kw = k - kh * 7;
        const int hh = h + kh - 3;                           // per-lane
        const int ww = w + kw - 3;
        const bool ok = (hh >= 0) & (hh < Hh) & (ww >= 0) & (ww < Ww);
        const float kv = ok ? ker[j] : 0.f;                  // one cndmask
        const int  off = ok ? hh * Ww + ww : 0;              // safe clamped addr
        const float* xr = xg + off;
#pragma unroll
        for (int c = 0; c < 16; ++c)
            acc[c] = fmaf(xr[(size_t)c * HW], kv, acc[c]);   // coalesced per c
        __builtin_amdgcn_sched_barrier(0);                   // bound in-flight loads
    }
}

// ---------------------------------------------------------------------------
// k2: fused kernel-gen + involution.
// grid (196, 4) x 256; wave wv -> group g = by*4+wv; lane -> px.
// waves_per_eu(4,4): register budget pinned at 128 VGPR -> no spill.
// ---------------------------------------------------------------------------
__attribute__((amdgpu_waves_per_eu(4, 4)))
__global__ void __launch_bounds__(256)
k2_involution(const float* __restrict__ x, const float* __restrict__ t,
              const float* __restrict__ w2t, const float* __restrict__ b2,
              float* __restrict__ out)
{
    const int lane = threadIdx.x & 63;
    const int wv   = __builtin_amdgcn_readfirstlane(threadIdx.x >> 6);  // 0..3
    const int pxt  = blockIdx.x;                             // 0..195
    const int g    = __builtin_amdgcn_readfirstlane((int)blockIdx.y * 4 + wv);
    const int px   = pxt * 64 + lane;
    const int n    = __builtin_amdgcn_readfirstlane(pxt / 49);  // 49 tiles/image
    const int hw   = px - n * HW;
    const int h    = hw / Ww;                                // per-lane
    const int w    = hw - h * Ww;

    const float* tp = t + px;
    const CONST_AS float* wg  = cptr(w2t) + g * 64;
    const CONST_AS float* b2g = cptr(b2) + g * KK;
    const float* xg = x + (size_t)n * Cc * HW + (size_t)(g * 16) * HW;

    float acc[16];
#pragma unroll
    for (int i = 0; i < 16; ++i) acc[i] = 0.f;

    do_chunk< 0, 25>(tp, wg, b2g, xg, h, w, acc);
    do_chunk<25, 24>(tp, wg, b2g, xg, h, w, acc);

    float* og = out + (size_t)n * Cc * HW + (size_t)(g * 16) * HW + hw;
#pragma unroll
    for (int c = 0; c < 16; ++c)
        og[(size_t)c * HW] = acc[c];                         // coalesced per c
}

// ---------------------------------------------------------------------------
extern "C" void kernel_launch(void* const* d_in, const int* in_sizes, int n_in,
                              void* d_out, int out_size, void* d_ws, size_t ws_size,
                              hipStream_t stream)
{
    const float* x     = (const float*)d_in[0];
    const float* w1    = (const float*)d_in[1];
    const float* b1    = (const float*)d_in[2];
    const float* gamma = (const float*)d_in[3];
    const float* beta  = (const float*)d_in[4];
    const float* mean  = (const float*)d_in[5];
    const float* var   = (const float*)d_in[6];
    const float* w2    = (const float*)d_in[7];
    const float* b2    = (const float*)d_in[8];

    float* ws  = (float*)d_ws;        // ~3.5 MB total
    float* w1f = ws + WS_W1F;
    float* bf  = ws + WS_BF;
    float* w2t = ws + WS_W2T;
    float* t   = ws + WS_T;
    float* out = (float*)d_out;

    k0_prep<<<dim3(256), 256, 0, stream>>>(
        w1, b1, gamma, beta, mean, var, w2, w1f, bf, w2t);
    k1_conv_bn_relu<<<dim3(NPX / 64, 2), 256, 0, stream>>>(x, w1f, bf, t);
    k2_involution<<<dim3(NPX / 64, 4), 256, 0, stream>>>(x, t, w2t, b2, out);
}

// Round 9
// 242.802 us; speedup vs baseline: 2.6544x; 1.4607x over previous
//
#include <hip/hip_runtime.h>

// Involution (RedNet-style), N=4 C=256 H=W=56, K=7, G=16, ratio=4 (Cr=64).
// k0: fold BN into w1f/bf; repack w2 -> w2t[g][kh][o][8] (7 weights + pad).
// k1: conv1 GEMM, weights via constant-address-space s_loads.
// k2: fused kernel-gen + involution, chunked BY KERNEL ROW (7 taps):
//     per kh: ker[7] streamed over o (t coalesced, weights 32B-aligned
//     s_loads), then one-x-row gather. Live set ~35 VGPR -> cannot spill.
//     Block = 1 group x 4 px-tiles (waves share the 14KB weight slice).

#define CONST_AS __attribute__((address_space(4)))

namespace {
constexpr int Nn  = 4;
constexpr int Cc  = 256;
constexpr int Hh  = 56;
constexpr int Ww  = 56;
constexpr int HW  = Hh * Ww;        // 3136
constexpr int NPX = Nn * HW;        // 12544
constexpr int Cr  = 64;             // reduced channels
constexpr int Gg  = 16;             // groups

// workspace layout (floats)
constexpr size_t WS_W1F = 0;                          // [256][64]
constexpr size_t WS_BF  = WS_W1F + (size_t)Cc * Cr;   // [64]
constexpr size_t WS_W2T = WS_BF  + Cr;                // [16][7][64][8]
constexpr size_t WS_T   = WS_W2T + (size_t)Gg * 7 * Cr * 8;  // [64][12544]

// CK-style cast to constant address space: uniform loads become s_load_*.
__device__ __forceinline__ const CONST_AS float* cptr(const float* p) {
    return (const CONST_AS float*)(unsigned long long)p;
}
}

// ---------------------------------------------------------------------------
// k0: weight prep.  w1f[c][o] = w1[o][c]*sc[o]; bf = folded bias;
//     w2t[g][kh][o][j] = w2[(g*49+kh*7+j)][o] for j<7, else 0.
// ---------------------------------------------------------------------------
__global__ void __launch_bounds__(256)
k0_prep(const float* __restrict__ w1, const float* __restrict__ b1,
        const float* __restrict__ gamma, const float* __restrict__ beta,
        const float* __restrict__ mean,  const float* __restrict__ var,
        const float* __restrict__ w2,
        float* __restrict__ w1f, float* __restrict__ bf, float* __restrict__ w2t)
{
    const int id = blockIdx.x * 256 + threadIdx.x;           // 0 .. 65535
    if (id < Cc * Cr) {
        const int c = id / Cr, o = id - c * Cr;
        const float sc = gamma[o] * rsqrtf(var[o] + 1e-5f);
        w1f[id] = w1[o * Cc + c] * sc;
        if (id < Cr)
            bf[id] = fmaf(b1[id] - mean[id], gamma[id] * rsqrtf(var[id] + 1e-5f),
                          beta[id]);
    }
    if (id < Gg * 7 * Cr * 8) {                              // 57344
        const int g  = id / (7 * Cr * 8);
        const int r  = id - g * (7 * Cr * 8);
        const int kh = r / (Cr * 8);
        const int r2 = r - kh * (Cr * 8);
        const int o  = r2 >> 3;
        const int j  = r2 & 7;
        w2t[id] = (j < 7) ? w2[((g * 49 + kh * 7 + j)) * Cr + o] : 0.f;
    }
}

// ---------------------------------------------------------------------------
// k1: 1x1 conv + folded BN + ReLU.
// grid (196, 2) x 256. lane = px; wave wv covers o = by*32 + wv*8 .. +8.
// ---------------------------------------------------------------------------
__global__ void __launch_bounds__(256)
k1_conv_bn_relu(const float* __restrict__ x, const float* __restrict__ w1f,
                const float* __restrict__ bf, float* __restrict__ t)
{
    const int lane = threadIdx.x & 63;
    const int wv   = __builtin_amdgcn_readfirstlane(threadIdx.x >> 6);  // 0..3
    const int px   = blockIdx.x * 64 + lane;                 // exact: 196*64=12544
    const int o0   = __builtin_amdgcn_readfirstlane((int)blockIdx.y * 32 + wv * 8);

    const int n  = px / HW;
    const int hw = px - n * HW;
    const float* xb = x + (size_t)n * Cc * HW + hw;
    const CONST_AS float* wf = cptr(w1f) + o0;

    float acc[8];
#pragma unroll
    for (int i = 0; i < 8; ++i) acc[i] = 0.f;

    float xv[8];
#pragma unroll
    for (int i = 0; i < 8; ++i) xv[i] = xb[(size_t)i * HW];  // coalesced batch

#pragma unroll 1
    for (int c0 = 0; c0 < Cc; c0 += 8) {
        float xn[8];
#pragma unroll
        for (int i = 0; i < 8; ++i)                           // prefetch (wraps @end)
            xn[i] = xb[(size_t)((c0 + 8 + i) & (Cc - 1)) * HW];
#pragma unroll
        for (int cc = 0; cc < 8; ++cc) {
            const CONST_AS float* wr = wf + (c0 + cc) * Cr;   // uniform -> s_load x8
#pragma unroll
            for (int i = 0; i < 8; ++i)
                acc[i] = fmaf(xv[cc], wr[i], acc[i]);
        }
#pragma unroll
        for (int i = 0; i < 8; ++i) xv[i] = xn[i];
    }

#pragma unroll
    for (int i = 0; i < 8; ++i) {
        const float v = acc[i] + bf[o0 + i];
        t[(size_t)(o0 + i) * NPX + px] = v > 0.f ? v : 0.f;  // coalesced store
    }
}

// ---------------------------------------------------------------------------
// k2: fused kernel-gen + involution, row-chunked.
// grid (49, 16) x 256. wave wv -> px-tile = bx*4+wv (same g for all waves).
// Per kh (skip if whole wave OOB):
//   Phase A: ker[7] = b2 row + sum_o t[o][px] * w2t[g][kh][o][0..6]
//   Phase B: one x row, 7 shifted taps x 16 channels into acc[16].
// ---------------------------------------------------------------------------
__global__ void __launch_bounds__(256)
k2_involution(const float* __restrict__ x, const float* __restrict__ t,
              const float* __restrict__ w2t, const float* __restrict__ b2,
              float* __restrict__ out)
{
    const int lane = threadIdx.x & 63;
    const int wv   = __builtin_amdgcn_readfirstlane(threadIdx.x >> 6);  // 0..3
    const int g    = __builtin_amdgcn_readfirstlane((int)blockIdx.y);
    const int tile = __builtin_amdgcn_readfirstlane((int)blockIdx.x * 4 + wv);
    const int n    = __builtin_amdgcn_readfirstlane(tile / 49);  // 49 tiles/image
    const int px   = tile * 64 + lane;
    const int hw   = px - n * HW;
    const int h    = hw / Ww;                                // per-lane (2 rows/tile)
    const int w    = hw - h * Ww;
    const int base = __builtin_amdgcn_readfirstlane(tile * 64 - n * HW);
    const int r0   = base / Ww;                              // first row in tile
    const int r1   = (base + 63) / Ww;                       // last row in tile

    const float* tp = t + px;
    const CONST_AS float* wg  = cptr(w2t) + (size_t)g * 7 * Cr * 8;
    const CONST_AS float* b2g = cptr(b2) + g * 49;
    const float* xg = x + (size_t)n * Cc * HW + (size_t)(g * 16) * HW;

    float acc[16];
#pragma unroll
    for (int i = 0; i < 16; ++i) acc[i] = 0.f;

#pragma unroll 1
    for (int kh = 0; kh < 7; ++kh) {
        if (r1 + kh < 3 || r0 + kh - 3 >= Hh) continue;      // whole wave OOB

        // ---- Phase A: ker[7] for this kernel row ----
        float ker[7];
#pragma unroll
        for (int j = 0; j < 7; ++j) ker[j] = b2g[kh * 7 + j];

        const CONST_AS float* wrow = wg + kh * (Cr * 8);
        float tv = tp[0];
#pragma unroll 1
        for (int o = 0; o < Cr; ++o) {
            const float tc = tv;
            tv = tp[(size_t)((o + 1) & (Cr - 1)) * NPX];     // 1-deep prefetch
            const CONST_AS float* wr = wrow + o * 8;         // 32B-aligned slice
#pragma unroll
            for (int j = 0; j < 7; ++j)
                ker[j] = fmaf(tc, wr[j], ker[j]);            // SGPR operand
        }

        // ---- Phase B: gather one x row ----
        const int hh = h + kh - 3;                           // per-lane
        const bool hok = (hh >= 0) & (hh < Hh);
#pragma unroll
        for (int kw = 0; kw < 7; ++kw) {
            const int ww = w + kw - 3;
            const bool ok = hok & (ww >= 0) & (ww < Ww);
            const float kv = ok ? ker[kw] : 0.f;             // one cndmask
            const int  off = ok ? hh * Ww + ww : 0;          // safe clamped addr
            const float* xr = xg + off;
#pragma unroll
            for (int c = 0; c < 16; ++c)
                acc[c] = fmaf(xr[(size_t)c * HW], kv, acc[c]);  // coalesced per c
            __builtin_amdgcn_sched_barrier(0);               // bound load clustering
        }
    }

    // ---- store: out[n][g*16+c][hw] ----
    float* og = out + (size_t)n * Cc * HW + (size_t)(g * 16) * HW + hw;
#pragma unroll
    for (int c = 0; c < 16; ++c)
        og[(size_t)c * HW] = acc[c];                         // coalesced per c
}

// ---------------------------------------------------------------------------
extern "C" void kernel_launch(void* const* d_in, const int* in_sizes, int n_in,
                              void* d_out, int out_size, void* d_ws, size_t ws_size,
                              hipStream_t stream)
{
    const float* x     = (const float*)d_in[0];
    const float* w1    = (const float*)d_in[1];
    const float* b1    = (const float*)d_in[2];
    const float* gamma = (const float*)d_in[3];
    const float* beta  = (const float*)d_in[4];
    const float* mean  = (const float*)d_in[5];
    const float* var   = (const float*)d_in[6];
    const float* w2    = (const float*)d_in[7];
    const float* b2    = (const float*)d_in[8];

    float* ws  = (float*)d_ws;        // ~3.5 MB total
    float* w1f = ws + WS_W1F;
    float* bf  = ws + WS_BF;
    float* w2t = ws + WS_W2T;
    float* t   = ws + WS_T;
    float* out = (float*)d_out;

    k0_prep<<<dim3(256), 256, 0, stream>>>(
        w1, b1, gamma, beta, mean, var, w2, w1f, bf, w2t);
    k1_conv_bn_relu<<<dim3(NPX / 64, 2), 256, 0, stream>>>(x, w1f, bf, t);
    k2_involution<<<dim3(49, Gg), 256, 0, stream>>>(x, t, w2t, b2, out);
}

// Round 10
// 98.217 us; speedup vs baseline: 6.5620x; 2.4721x over previous
//
#include <hip/hip_runtime.h>

// Involution (RedNet-style), N=4 C=256 H=W=56, K=7, G=16, ratio=4 (Cr=64).
// k0: fold BN into w1f/bf; repack w2 -> w2t[g][kh][o][8].
// k1: conv1 GEMM; x-tile staged in LDS (32-deep MLP), 8 waves x 8 outputs,
//     weights via constant-address-space s_loads.
// k2: fused kernel-gen + involution. t-tile staged in LDS once; 4 waves
//     split the 7 kernel rows; ker[7] per (lane,kh) from LDS t + SGPR
//     weights; x gather with bounded clustering (no sched_barriers);
//     4-wave LDS reduction.

#define CONST_AS __attribute__((address_space(4)))

namespace {
constexpr int Nn  = 4;
constexpr int Cc  = 256;
constexpr int Hh  = 56;
constexpr int Ww  = 56;
constexpr int HW  = Hh * Ww;        // 3136
constexpr int NPX = Nn * HW;        // 12544
constexpr int Cr  = 64;             // reduced channels
constexpr int Gg  = 16;             // groups

// workspace layout (floats)
constexpr size_t WS_W1F = 0;                          // [256][64]
constexpr size_t WS_BF  = WS_W1F + (size_t)Cc * Cr;   // [64]
constexpr size_t WS_W2T = WS_BF  + Cr;                // [16][7][64][8]
constexpr size_t WS_T   = WS_W2T + (size_t)Gg * 7 * Cr * 8;  // [64][12544]

// CK-style cast to constant address space: uniform loads become s_load_*.
__device__ __forceinline__ const CONST_AS float* cptr(const float* p) {
    return (const CONST_AS float*)(unsigned long long)p;
}
}

// ---------------------------------------------------------------------------
// k0: weight prep.  w1f[c][o] = w1[o][c]*sc[o]; bf = folded bias;
//     w2t[g][kh][o][j] = w2[(g*49+kh*7+j)][o] for j<7, else 0.
// ---------------------------------------------------------------------------
__global__ void __launch_bounds__(256)
k0_prep(const float* __restrict__ w1, const float* __restrict__ b1,
        const float* __restrict__ gamma, const float* __restrict__ beta,
        const float* __restrict__ mean,  const float* __restrict__ var,
        const float* __restrict__ w2,
        float* __restrict__ w1f, float* __restrict__ bf, float* __restrict__ w2t)
{
    const int id = blockIdx.x * 256 + threadIdx.x;           // 0 .. 65535
    if (id < Cc * Cr) {
        const int c = id / Cr, o = id - c * Cr;
        const float sc = gamma[o] * rsqrtf(var[o] + 1e-5f);
        w1f[id] = w1[o * Cc + c] * sc;
        if (id < Cr)
            bf[id] = fmaf(b1[id] - mean[id], gamma[id] * rsqrtf(var[id] + 1e-5f),
                          beta[id]);
    }
    if (id < Gg * 7 * Cr * 8) {                              // 57344
        const int g  = id / (7 * Cr * 8);
        const int r  = id - g * (7 * Cr * 8);
        const int kh = r / (Cr * 8);
        const int r2 = r - kh * (Cr * 8);
        const int o  = r2 >> 3;
        const int j  = r2 & 7;
        w2t[id] = (j < 7) ? w2[((g * 49 + kh * 7 + j)) * Cr + o] : 0.f;
    }
}

// ---------------------------------------------------------------------------
// k1: 1x1 conv + folded BN + ReLU.
// grid (196) x 512. Block stages x-tile [256 c][64 px] in LDS (64 KB) with
// 32 loads/thread all in flight; wave wv computes o = wv*8 .. +8 from LDS
// against s_load weight rows. t layout [64][12544].
// ---------------------------------------------------------------------------
__global__ void __launch_bounds__(512)
k1_conv_bn_relu(const float* __restrict__ x, const float* __restrict__ w1f,
                const float* __restrict__ bf, float* __restrict__ t)
{
    __shared__ float xs[Cc][64];                             // 64 KB

    const int tid  = threadIdx.x;
    const int lane = tid & 63;
    const int q    = __builtin_amdgcn_readfirstlane(tid >> 6);   // 0..7
    const int tile = __builtin_amdgcn_readfirstlane((int)blockIdx.x); // 0..195
    const int n    = __builtin_amdgcn_readfirstlane(tile / 49);
    const int hwb  = __builtin_amdgcn_readfirstlane((tile - n * 49) * 64);
    const int px   = tile * 64 + lane;

    // ---- stage x-tile: thread loads c = q + 8*i (32 loads, all in flight) ----
    const float* xb = x + (size_t)n * Cc * HW + hwb + lane;
    float v[32];
#pragma unroll
    for (int i = 0; i < 32; ++i)
        v[i] = xb[(size_t)(q + 8 * i) * HW];                 // coalesced
#pragma unroll
    for (int i = 0; i < 32; ++i)
        xs[q + 8 * i][lane] = v[i];
    __syncthreads();

    // ---- compute: wave q owns o0 = q*8 ----
    const int o0 = q * 8;
    const CONST_AS float* wf = cptr(w1f) + o0;
    float acc[8];
#pragma unroll
    for (int i = 0; i < 8; ++i) acc[i] = 0.f;

#pragma unroll 4
    for (int c = 0; c < Cc; ++c) {
        const float xv = xs[c][lane];                        // 2-way, free
        const CONST_AS float* wr = wf + c * Cr;              // s_load_dwordx8
#pragma unroll
        for (int i = 0; i < 8; ++i)
            acc[i] = fmaf(xv, wr[i], acc[i]);
    }

    const CONST_AS float* bfc = cptr(bf) + o0;
#pragma unroll
    for (int i = 0; i < 8; ++i) {
        const float vv = acc[i] + bfc[i];
        t[(size_t)(o0 + i) * NPX + px] = vv > 0.f ? vv : 0.f;  // coalesced
    }
}

// ---------------------------------------------------------------------------
// k2: fused kernel-gen + involution.
// grid (196, 16) x 256. block = (px-tile, g). Stage t-tile [64 o][64 px]
// in LDS; wave wv handles kh in {wv, wv+4}; per kh: ker[7] from LDS t +
// SGPR weights, then one-x-row gather (unroll 2 bounds clustering);
// 4-wave LDS reduce of acc[16].
// ---------------------------------------------------------------------------
__global__ void __launch_bounds__(256)
k2_involution(const float* __restrict__ x, const float* __restrict__ t,
              const float* __restrict__ w2t, const float* __restrict__ b2,
              float* __restrict__ out)
{
    __shared__ float ts[Cr][64];                             // 16 KB
    __shared__ float red[4][16][64];                         // 16 KB

    const int lane = threadIdx.x & 63;
    const int wv   = __builtin_amdgcn_readfirstlane(threadIdx.x >> 6);  // 0..3
    const int tile = __builtin_amdgcn_readfirstlane((int)blockIdx.x);   // 0..195
    const int g    = __builtin_amdgcn_readfirstlane((int)blockIdx.y);
    const int n    = __builtin_amdgcn_readfirstlane(tile / 49);
    const int px   = tile * 64 + lane;
    const int hw   = px - n * HW;
    const int h    = hw / Ww;                                // per-lane
    const int w    = hw - h * Ww;
    const int base = __builtin_amdgcn_readfirstlane(tile * 64 - n * HW);
    const int r0   = base / Ww;                              // first row in tile
    const int r1   = (base + 63) / Ww;                       // last row in tile

    // ---- stage t-tile: wave wv loads o = wv + 4*i (16 loads in flight) ----
    {
        const float* tb = t + px;
        float v[16];
#pragma unroll
        for (int i = 0; i < 16; ++i)
            v[i] = tb[(size_t)(wv + 4 * i) * NPX];           // coalesced
#pragma unroll
        for (int i = 0; i < 16; ++i)
            ts[wv + 4 * i][lane] = v[i];
    }
    __syncthreads();

    float acc[16];
#pragma unroll
    for (int i = 0; i < 16; ++i) acc[i] = 0.f;

    const CONST_AS float* wg  = cptr(w2t) + (size_t)g * 7 * Cr * 8;
    const CONST_AS float* b2g = cptr(b2) + g * 49;
    const float* xg = x + (size_t)n * Cc * HW + (size_t)(g * 16) * HW;

#pragma unroll 1
    for (int s = 0; s < 2; ++s) {
        const int kh = wv + 4 * s;                           // {0,4}{1,5}{2,6}{3}
        if (kh > 6) break;                                   // wv=3, s=1
        if (r1 + kh < 3 || r0 + kh - 3 >= Hh) continue;      // whole wave OOB

        // ---- Phase A: ker[7] from LDS t + SGPR weight slices ----
        float ker[7];
#pragma unroll
        for (int j = 0; j < 7; ++j) ker[j] = b2g[kh * 7 + j];

        const CONST_AS float* wrow = wg + kh * (Cr * 8);
#pragma unroll 4
        for (int o = 0; o < Cr; ++o) {
            const float tc = ts[o][lane];                    // LDS, 2-way free
            const CONST_AS float* wr = wrow + o * 8;         // s_load_dwordx8
#pragma unroll
            for (int j = 0; j < 7; ++j)
                ker[j] = fmaf(tc, wr[j], ker[j]);
        }

        // ---- Phase B: gather one x row (MLP allowed, clustering bounded) ----
        const int hh = h + kh - 3;                           // per-lane
        const bool hok = (hh >= 0) & (hh < Hh);
#pragma unroll 2
        for (int kw = 0; kw < 7; ++kw) {
            const int ww = w + kw - 3;
            const bool ok = hok & (ww >= 0) & (ww < Ww);
            const float kv = ok ? ker[kw] : 0.f;             // one cndmask
            const int  off = ok ? hh * Ww + ww : 0;          // safe clamped addr
            const float* xr = xg + off;
#pragma unroll
            for (int c = 0; c < 16; ++c)
                acc[c] = fmaf(xr[(size_t)c * HW], kv, acc[c]);  // coalesced per c
        }
    }

    // ---- 4-wave reduction + store ----
#pragma unroll
    for (int c = 0; c < 16; ++c)
        red[wv][c][lane] = acc[c];
    __syncthreads();

    float* og = out + (size_t)n * Cc * HW + (size_t)(g * 16) * HW + hw;
#pragma unroll
    for (int j = 0; j < 4; ++j) {
        const int c = wv * 4 + j;
        og[(size_t)c * HW] = red[0][c][lane] + red[1][c][lane]
                           + red[2][c][lane] + red[3][c][lane];  // coalesced
    }
}

// ---------------------------------------------------------------------------
extern "C" void kernel_launch(void* const* d_in, const int* in_sizes, int n_in,
                              void* d_out, int out_size, void* d_ws, size_t ws_size,
                              hipStream_t stream)
{
    const float* x     = (const float*)d_in[0];
    const float* w1    = (const float*)d_in[1];
    const float* b1    = (const float*)d_in[2];
    const float* gamma = (const float*)d_in[3];
    const float* beta  = (const float*)d_in[4];
    const float* mean  = (const float*)d_in[5];
    const float* var   = (const float*)d_in[6];
    const float* w2    = (const float*)d_in[7];
    const float* b2    = (const float*)d_in[8];

    float* ws  = (float*)d_ws;        // ~3.5 MB total
    float* w1f = ws + WS_W1F;
    float* bf  = ws + WS_BF;
    float* w2t = ws + WS_W2T;
    float* t   = ws + WS_T;
    float* out = (float*)d_out;

    k0_prep<<<dim3(256), 256, 0, stream>>>(
        w1, b1, gamma, beta, mean, var, w2, w1f, bf, w2t);
    k1_conv_bn_relu<<<dim3(196), 512, 0, stream>>>(x, w1f, bf, t);
    k2_involution<<<dim3(196, Gg), 256, 0, stream>>>(x, t, w2t, b2, out);
}